// Round 8
// baseline (223.427 us; speedup 1.0000x reference)
//
#include <hip/hip_runtime.h>
#include <hip/hip_bf16.h>

// ---------------------------------------------------------------------------
// 2-layer GCN:  x1 = relu(Agg(x @ W1) + b1);  out = relu(Agg(x1 @ W2) + b2)
// Agg: out[d] = dinv[d] * ( sum_{e: dst=d} hn[src_e] + hn[d] ),
//      hn[i] = (x@W)[i] * dinv[i]  (bf16),  dinv = rsqrt(deg+1).
// GEMM via v_mfma_f32_16x16x32_bf16; 64-col W halves -> 34.8KB LDS, 4 blk/CU.
// CSR: fixed-stride 512-node buckets, bucket-local LDS randomness only.
// Aggregate: 16B/lane row gathers, 4 chains/16-lane group, csr prefetch.
// Non-temporal loads/stores on all read-once/write-once streams so L2 keeps
// the hn gather working set.
// ---------------------------------------------------------------------------

#define F 128
#define BN 512
#define LOG_BN 9
#define MAXB 512
#define EPB 4096
#define CAP 10240          // edges per bucket region (fixed stride)
#define WSTRIDE 136        // padded u16 stride (2-way max LDS bank aliasing)

typedef __attribute__((ext_vector_type(8))) short bh8;
typedef __attribute__((ext_vector_type(4))) float f32x4;
typedef __attribute__((ext_vector_type(4))) unsigned int u32x4;
typedef __attribute__((ext_vector_type(2))) unsigned int u32x2;

__device__ __forceinline__ unsigned short f2bf(float f) {
    __hip_bfloat16 h = __float2bfloat16(f);
    return *reinterpret_cast<unsigned short*>(&h);
}

__device__ __forceinline__ void acc8(float* a, u32x4 q) {
    a[0] += __uint_as_float(q[0] << 16);
    a[1] += __uint_as_float(q[0] & 0xFFFF0000u);
    a[2] += __uint_as_float(q[1] << 16);
    a[3] += __uint_as_float(q[1] & 0xFFFF0000u);
    a[4] += __uint_as_float(q[2] << 16);
    a[5] += __uint_as_float(q[2] & 0xFFFF0000u);
    a[6] += __uint_as_float(q[3] << 16);
    a[7] += __uint_as_float(q[3] & 0xFFFF0000u);
}

// ----------------------------- CSR build ----------------------------------
// scatter packed (dlocal<<20 | src) into fixed-stride bucket regions
__global__ __launch_bounds__(256) void bucket_scatter_kernel(
    const int* __restrict__ src, const int* __restrict__ dst, int E,
    int* __restrict__ gfill, unsigned int* __restrict__ pairs) {
    __shared__ int cnt[MAXB];
    __shared__ int base_l[MAXB];
    int t = threadIdx.x;
    for (int k = t; k < MAXB; k += 256) cnt[k] = 0;
    __syncthreads();
    int base = blockIdx.x * EPB;
    int d[16], r[16];
#pragma unroll
    for (int j = 0; j < 16; ++j) {
        int e = base + j * 256 + t;
        d[j] = -1; r[j] = 0;
        if (e < E) {
            d[j] = __builtin_nontemporal_load(dst + e);
            r[j] = atomicAdd(&cnt[d[j] >> LOG_BN], 1);
        }
    }
    __syncthreads();
    for (int k = t; k < MAXB; k += 256)
        base_l[k] = cnt[k] ? atomicAdd(&gfill[k], cnt[k]) : 0;
    __syncthreads();
#pragma unroll
    for (int j = 0; j < 16; ++j) {
        int e = base + j * 256 + t;
        if (e < E) {
            int b = d[j] >> LOG_BN;
            int pos = base_l[b] + r[j];
            if (pos < CAP) {
                unsigned int w = (unsigned int)__builtin_nontemporal_load(src + e) |
                                 ((unsigned int)(d[j] & (BN - 1)) << 20);
                pairs[(size_t)b * CAP + pos] = w;
            }
        }
    }
}

// per-bucket: LDS-stage pairs, degree count, scan -> offs2/dinv, csr scatter
__global__ __launch_bounds__(512) void bucket_build_kernel(
    const unsigned int* __restrict__ pairs, const int* __restrict__ gfill,
    int N, int2* __restrict__ offs2, float* __restrict__ dinv,
    int* __restrict__ csr) {
    __shared__ unsigned int spair[CAP];
    __shared__ int deg[BN];
    __shared__ int fill[BN];
    __shared__ int sc[BN];
    int b = blockIdx.x, t = threadIdx.x;
    int node0 = b << LOG_BN;
    int nN = min(BN, N - node0);
    int lo = b * CAP;
    int cnt = min(gfill[b], CAP);
    deg[t] = 0; fill[t] = 0;
    for (int i = t; i < cnt; i += 512)
        spair[i] = __builtin_nontemporal_load(pairs + (size_t)lo + i);
    __syncthreads();
    for (int i = t; i < cnt; i += 512)
        atomicAdd(&deg[(spair[i] >> 20) & (BN - 1)], 1);
    __syncthreads();
    int v = deg[t];
    sc[t] = v;
    __syncthreads();
    for (int off = 1; off < BN; off <<= 1) {
        int x = (t >= off) ? sc[t - off] : 0;
        __syncthreads();
        sc[t] += x;
        __syncthreads();
    }
    int ex = sc[t] - v;
    if (t < nN) {
        int beg = lo + ex;
        offs2[node0 + t] = make_int2(beg, beg + v);
        dinv[node0 + t] = rsqrtf((float)v + 1.0f);
    }
    __syncthreads();
    sc[t] = ex;
    __syncthreads();
    for (int i = t; i < cnt; i += 512) {
        unsigned int w = spair[i];
        int dl = (w >> 20) & (BN - 1);
        int rr = atomicAdd(&fill[dl], 1);
        csr[lo + sc[dl] + rr] = (int)(w & 0xFFFFFu);
    }
}

// ---------------- W1,W2 -> Wt bf16 padded [128][WSTRIDE] -------------------
__global__ __launch_bounds__(256) void wt_prep_kernel(
    const float* __restrict__ W1, const float* __restrict__ W2,
    unsigned short* __restrict__ wt1, unsigned short* __restrict__ wt2) {
    int gid = blockIdx.x * 256 + threadIdx.x;   // 0..4095
    const float* W = (gid < 2048) ? W1 : W2;
    unsigned short* wt = (gid < 2048) ? wt1 : wt2;
    int g = gid & 2047;
    int n = g >> 4;
    int kc = (g & 15) * 8;
    unsigned short u[8];
#pragma unroll
    for (int j = 0; j < 8; ++j) u[j] = f2bf(W[(size_t)(kc + j) * F + n]);
    u32x4 v;
    v[0] = (unsigned)u[0] | ((unsigned)u[1] << 16);
    v[1] = (unsigned)u[2] | ((unsigned)u[3] << 16);
    v[2] = (unsigned)u[4] | ((unsigned)u[5] << 16);
    v[3] = (unsigned)u[6] | ((unsigned)u[7] << 16);
    *(u32x4*)&wt[(size_t)n * WSTRIDE + kc] = v;
}

// --------------------------- MFMA GEMM ------------------------------------
// 128 rows per block (2 row-tiles of 64); per row-tile, two 64-col W halves
// staged from the L2-resident wt image. 34.8KB LDS -> 4 blocks/CU.
template <bool A_BF16>
__global__ __launch_bounds__(256) void gemm_mfma_kernel(
    const void* __restrict__ Ain, const unsigned short* __restrict__ wt,
    const float* __restrict__ dinv, unsigned short* __restrict__ hn, int N) {
    __shared__ unsigned short sA[64 * WSTRIDE];
    __shared__ unsigned short sW[64 * WSTRIDE];
    int t = threadIdx.x;
    int wid = t >> 6, lane = t & 63;
    int lr = lane & 15, lk = lane >> 4;

#pragma unroll
    for (int rt = 0; rt < 2; ++rt) {
        int row0 = blockIdx.x * 128 + rt * 64;
        if (row0 >= N) break;               // block-uniform

        // ---- stage A tile (64 rows) ----
        if (A_BF16) {
            const unsigned short* A = (const unsigned short*)Ain;
#pragma unroll
            for (int j = 0; j < 4; ++j) {
                int i = j * 256 + t;
                int r = i >> 4, c8 = i & 15;
                int grow = row0 + r;
                u32x4 v = (u32x4){0, 0, 0, 0};
                if (grow < N)
                    v = __builtin_nontemporal_load(
                        (const u32x4*)(A + (size_t)grow * F + c8 * 8));
                *(u32x4*)&sA[r * WSTRIDE + c8 * 8] = v;
            }
        } else {
            const float* A = (const float*)Ain;
#pragma unroll
            for (int j = 0; j < 8; ++j) {
                int i = j * 256 + t;
                int r = i >> 5, c4 = i & 31;
                int grow = row0 + r;
                f32x4 v = (f32x4){0.f, 0.f, 0.f, 0.f};
                if (grow < N)
                    v = __builtin_nontemporal_load(
                        (const f32x4*)(A + (size_t)grow * F + c4 * 4));
                u32x2 p;
                p[0] = (unsigned)f2bf(v[0]) | ((unsigned)f2bf(v[1]) << 16);
                p[1] = (unsigned)f2bf(v[2]) | ((unsigned)f2bf(v[3]) << 16);
                *(u32x2*)&sA[r * WSTRIDE + c4 * 4] = p;
            }
        }
        __syncthreads();

        // ---- preload A frags into registers ----
        bh8 af[4];
        const unsigned short* aP = &sA[(wid * 16 + lr) * WSTRIDE + lk * 8];
#pragma unroll
        for (int ks = 0; ks < 4; ++ks) af[ks] = *(const bh8*)(aP + ks * 32);
        __syncthreads();                    // sA free for epilogue reuse

        float dv[4];
        int rbase = wid * 16 + lk * 4;
#pragma unroll
        for (int j = 0; j < 4; ++j) {
            int grow = row0 + rbase + j;
            dv[j] = (grow < N) ? dinv[grow] : 0.f;
        }

#pragma unroll
        for (int ch = 0; ch < 2; ++ch) {
            // ---- stage W half (64 out-cols) ----
            {
                const u32x4* ws = (const u32x4*)(wt + (size_t)ch * 64 * WSTRIDE);
                u32x4* wd = (u32x4*)sW;
#pragma unroll
                for (int j = 0; j < 5; ++j) {
                    int i = j * 256 + t;
                    if (i < 64 * WSTRIDE / 8) wd[i] = ws[i];
                }
            }
            __syncthreads();

            f32x4 acc[4];
#pragma unroll
            for (int c = 0; c < 4; ++c) acc[c] = (f32x4){0.f, 0.f, 0.f, 0.f};

            const unsigned short* bP = &sW[lr * WSTRIDE + lk * 8];
#pragma unroll
            for (int ct = 0; ct < 4; ++ct) {
                const unsigned short* bq = bP + ct * 16 * WSTRIDE;
                bh8 b0 = *(const bh8*)(bq);
                bh8 b1 = *(const bh8*)(bq + 32);
                bh8 b2 = *(const bh8*)(bq + 64);
                bh8 b3 = *(const bh8*)(bq + 96);
                acc[ct] = __builtin_amdgcn_mfma_f32_16x16x32_bf16(af[0], b0, acc[ct], 0, 0, 0);
                acc[ct] = __builtin_amdgcn_mfma_f32_16x16x32_bf16(af[1], b1, acc[ct], 0, 0, 0);
                acc[ct] = __builtin_amdgcn_mfma_f32_16x16x32_bf16(af[2], b2, acc[ct], 0, 0, 0);
                acc[ct] = __builtin_amdgcn_mfma_f32_16x16x32_bf16(af[3], b3, acc[ct], 0, 0, 0);
            }

            // ---- epilogue: scale, bf16, repack via sA (cols 0..63) ----
#pragma unroll
            for (int ct = 0; ct < 4; ++ct) {
#pragma unroll
                for (int j = 0; j < 4; ++j)
                    sA[(rbase + j) * WSTRIDE + ct * 16 + lr] =
                        f2bf(acc[ct][j] * dv[j]);
            }
            __syncthreads();
#pragma unroll
            for (int j = 0; j < 2; ++j) {
                int i = j * 256 + t;        // 0..511: 64 rows x 8 chunks
                int r = i >> 3, c8 = i & 7;
                int grow = row0 + r;
                if (grow < N)
                    *(u32x4*)(hn + (size_t)grow * F + ch * 64 + c8 * 8) =
                        *(const u32x4*)&sA[r * WSTRIDE + c8 * 8];
            }
            __syncthreads();                // before next sW stage / sA reuse
        }
    }
}

// --------------------------- aggregation ----------------------------------
// 32 lanes per node: eo = lane>>4 (edge parity), cg = lane&15 (16B column
// group). Four gather chains in flight per 16-lane group; csr prefetched.
// Output stores are non-temporal (write-once; keep L2 for hn gathers).
template <bool OUT_BF16>
__global__ __launch_bounds__(256) void aggregate_kernel(
    const unsigned short* __restrict__ hn, const int* __restrict__ csr,
    const int2* __restrict__ offs2, const float* __restrict__ dinv,
    const float* __restrict__ bias, void* __restrict__ outv, int N) {
    int node = blockIdx.x * 8 + (threadIdx.x >> 5);
    if (node >= N) return;
    int half = threadIdx.x & 31;
    int eo = half >> 4;
    int cg = half & 15;

    const u32x4* hn4 = (const u32x4*)hn;   // 16 u32x4 per 256B row
    float a0[8], a1[8], a2[8], a3[8];
#pragma unroll
    for (int j = 0; j < 8; ++j) { a0[j] = 0.f; a1[j] = 0.f; a2[j] = 0.f; a3[j] = 0.f; }
    if (eo == 0) {                          // self-loop on parity-0 group
        u32x4 q = hn4[(size_t)node * 16 + cg];
        acc8(a0, q);
    }

    int2 oo = offs2[node];
    int e0 = oo.x + eo;                     // group's edges: e0, e0+2, ...
    int d = oo.y - e0;
    int cnt = (d <= 0) ? 0 : ((d + 1) >> 1);

    int i0 = (0 < cnt) ? __builtin_nontemporal_load(csr + e0)     : -1;
    int i1 = (1 < cnt) ? __builtin_nontemporal_load(csr + e0 + 2) : -1;
    int i2 = (2 < cnt) ? __builtin_nontemporal_load(csr + e0 + 4) : -1;
    int i3 = (3 < cnt) ? __builtin_nontemporal_load(csr + e0 + 6) : -1;
    int k = 0;
    while (k < cnt) {
        u32x4 q0 = (u32x4){0,0,0,0}, q1 = q0, q2 = q0, q3 = q0;
        if (i0 >= 0) q0 = hn4[(size_t)i0 * 16 + cg];
        if (i1 >= 0) q1 = hn4[(size_t)i1 * 16 + cg];
        if (i2 >= 0) q2 = hn4[(size_t)i2 * 16 + cg];
        if (i3 >= 0) q3 = hn4[(size_t)i3 * 16 + cg];
        int kn = k + 4;
        i0 = (kn     < cnt) ? __builtin_nontemporal_load(csr + e0 + 2 * kn)     : -1;
        i1 = (kn + 1 < cnt) ? __builtin_nontemporal_load(csr + e0 + 2 * kn + 2) : -1;
        i2 = (kn + 2 < cnt) ? __builtin_nontemporal_load(csr + e0 + 2 * kn + 4) : -1;
        i3 = (kn + 3 < cnt) ? __builtin_nontemporal_load(csr + e0 + 2 * kn + 6) : -1;
        acc8(a0, q0);
        acc8(a1, q1);
        acc8(a2, q2);
        acc8(a3, q3);
        k = kn;
    }

#pragma unroll
    for (int j = 0; j < 8; ++j) {
        a0[j] += a1[j];
        a2[j] += a3[j];
        a0[j] += a2[j];
        a0[j] += __shfl_xor(a0[j], 16, 32);
    }

    if (eo == 0) {
        float sc = dinv[node];
        f32x4 b0 = *((const f32x4*)bias + cg * 2);
        f32x4 b1 = *((const f32x4*)bias + cg * 2 + 1);
        float o[8];
        o[0] = fmaxf(fmaf(a0[0], sc, b0[0]), 0.f);
        o[1] = fmaxf(fmaf(a0[1], sc, b0[1]), 0.f);
        o[2] = fmaxf(fmaf(a0[2], sc, b0[2]), 0.f);
        o[3] = fmaxf(fmaf(a0[3], sc, b0[3]), 0.f);
        o[4] = fmaxf(fmaf(a0[4], sc, b1[0]), 0.f);
        o[5] = fmaxf(fmaf(a0[5], sc, b1[1]), 0.f);
        o[6] = fmaxf(fmaf(a0[6], sc, b1[2]), 0.f);
        o[7] = fmaxf(fmaf(a0[7], sc, b1[3]), 0.f);
        if (OUT_BF16) {
            u32x4 p;
            p[0] = (unsigned)f2bf(o[0]) | ((unsigned)f2bf(o[1]) << 16);
            p[1] = (unsigned)f2bf(o[2]) | ((unsigned)f2bf(o[3]) << 16);
            p[2] = (unsigned)f2bf(o[4]) | ((unsigned)f2bf(o[5]) << 16);
            p[3] = (unsigned)f2bf(o[6]) | ((unsigned)f2bf(o[7]) << 16);
            __builtin_nontemporal_store(p, (u32x4*)outv + (size_t)node * 16 + cg);
        } else {
            f32x4* op = (f32x4*)((float*)outv + (size_t)node * F + cg * 8);
            f32x4 q0 = (f32x4){o[0], o[1], o[2], o[3]};
            f32x4 q1 = (f32x4){o[4], o[5], o[6], o[7]};
            __builtin_nontemporal_store(q0, op);
            __builtin_nontemporal_store(q1, op + 1);
        }
    }
}

extern "C" void kernel_launch(void* const* d_in, const int* in_sizes, int n_in,
                              void* d_out, int out_size, void* d_ws, size_t ws_size,
                              hipStream_t stream) {
    const float* x   = (const float*)d_in[0];
    const int*   ei  = (const int*)d_in[1];   // int64 in reference -> int32 here
    const float* W1  = (const float*)d_in[2];
    const float* b1  = (const float*)d_in[3];
    const float* W2  = (const float*)d_in[4];
    const float* b2  = (const float*)d_in[5];
    float* out       = (float*)d_out;

    int N = in_sizes[0] / F;
    int E = in_sizes[1] / 2;
    const int* esrc = ei;
    const int* edst = ei + E;

    int nbkt = (N + BN - 1) / BN;

    char* w = (char*)d_ws;
    auto alloc = [&](size_t bytes) {
        char* p = w;
        w += (bytes + 255) & ~(size_t)255;
        return p;
    };
    int*   gfill   = (int*)alloc((size_t)MAXB * 4);
    int2*  offs2   = (int2*)alloc((size_t)N * 8);
    float* dinv    = (float*)alloc((size_t)N * 4);
    unsigned int* pairs = (unsigned int*)alloc((size_t)nbkt * CAP * 4);
    int*   csr     = (int*)alloc((size_t)nbkt * CAP * 4);
    unsigned short* hn  = (unsigned short*)alloc((size_t)N * F * 2);
    unsigned short* wt1 = (unsigned short*)alloc((size_t)F * WSTRIDE * 2);
    unsigned short* wt2 = (unsigned short*)alloc((size_t)F * WSTRIDE * 2);
    // layer-1 bf16 activations live in spare d_out space (51.2MB f32 buffer,
    // x1b needs 25.6MB; layer-2 aggregate fully overwrites d_out afterwards)
    unsigned short* x1b = (unsigned short*)d_out;

    hipMemsetAsync(gfill, 0, (size_t)MAXB * 4, stream);

    int nbe = (E + EPB - 1) / EPB;
    bucket_scatter_kernel<<<nbe, 256, 0, stream>>>(esrc, edst, E, gfill, pairs);
    bucket_build_kernel<<<nbkt, 512, 0, stream>>>(pairs, gfill, N, offs2, dinv, csr);
    wt_prep_kernel<<<16, 256, 0, stream>>>(W1, W2, wt1, wt2);

    int gblocks = (N + 127) / 128;
    int ablocks = (N + 7) / 8;

    // layer 1
    gemm_mfma_kernel<false><<<gblocks, 256, 0, stream>>>(x, wt1, dinv, hn, N);
    aggregate_kernel<true><<<ablocks, 256, 0, stream>>>(hn, csr, offs2, dinv, b1, x1b, N);
    // layer 2
    gemm_mfma_kernel<true><<<gblocks, 256, 0, stream>>>(x1b, wt2, dinv, hn, N);
    aggregate_kernel<false><<<ablocks, 256, 0, stream>>>(hn, csr, offs2, dinv, b2, out, N);
}